// Round 11
// baseline (779.963 us; speedup 1.0000x reference)
//
#include <hip/hip_runtime.h>
#include <hip/hip_bf16.h>

#define B_ROWS 8192
#define C_IN   4096
#define G_GRP  8
#define CG     512
#define J_RANK 512

// ---- fused GEMM geometry: 128x256 tile, BK=32, 8 waves (2x4), 64x64 wave ----
#define BM 128
#define BN 256
#define BK 32
#define NKT (CG / BK)                 // 16 K-tiles

typedef __attribute__((ext_vector_type(8))) short bf16x8;
typedef __attribute__((ext_vector_type(4))) float f32x4;
typedef __attribute__((ext_vector_type(8))) unsigned short u16x8;

struct ushort4v { unsigned short x, y, z, w; };

__device__ __forceinline__ unsigned short f2bf(float f) {
    unsigned int u = __float_as_uint(f);
    unsigned int r = (u + 0x7FFFu + ((u >> 16) & 1u)) >> 16;  // RNE
    return (unsigned short)r;
}

// ---------------- kernel 1: convert weights fp32 -> bf16 ----------------
__global__ __launch_bounds__(256) void convert_w_kernel(
    const float* __restrict__ w, unsigned short* __restrict__ wb, int n4) {
    int i = blockIdx.x * 256 + threadIdx.x;
    if (i >= n4) return;
    float4 v = ((const float4*)w)[i];
    ushort4v o;
    o.x = f2bf(v.x); o.y = f2bf(v.y); o.z = f2bf(v.z); o.w = f2bf(v.w);
    ((ushort4v*)wb)[i] = o;
}

// ------ kernel 2: FUSED gather + grouped GEMM (permute kernel deleted) ---
// A is staged straight from x (fp32, unpermuted) via per-thread scattered
// loads + f2bf + swizzled ds_write_b128, double-buffered one phase ahead.
// The gather's TA cost overlaps the gemm's (previously idle) MFMA pipeline
// instead of running as a 47us serial kernel. B staged via global_load_lds
// 2 K-tiles ahead (R9 scheme). Steady wait: ONE vmcnt(2) per kt
// (in-order retire: [B(kt+1),scat8] done, B(kt+2) in flight).
// LDS: A 2x8KB + B 2x16KB + idx 2KB = 50KB.
__global__ __launch_bounds__(512, 4) void fused_gemm_kernel(
    const float* __restrict__ X,             // [B][4096] fp32 (natural order)
    const int* __restrict__ arr,             // arrangements
    const unsigned short* __restrict__ Wb,   // [G][J][CG] bf16
    const float* __restrict__ bias,          // [G][J]
    float* __restrict__ out) {               // [B][4096] fp32
    __shared__ unsigned short ldsA[2][BM * BK];   // 2 x 8 KB
    __shared__ unsigned short ldsB[2][BN * BK];   // 2 x 16 KB
    __shared__ int ldsIdx[CG];                    // 2 KB

    const int tid = threadIdx.x;
    const int g   = blockIdx.x & 7;    // group -> XCD pin
    const int idx = blockIdx.x >> 3;   // 0..127
    const int mt  = idx >> 1;          // 0..63
    const int nt  = idx & 1;

    const int l   = tid & 63;
    const int wv  = tid >> 6;          // 0..7
    const int wr  = wv >> 2;           // 0..1
    const int wc  = wv & 3;            // 0..3
    const int lr  = l & 15;
    const int lkq = l >> 4;            // 0..3

    // arrangements declared int64 in the reference; harness may hand int32.
    const bool is64 = (arr[1] == 0 && arr[3] == 0 && arr[5] == 0 && arr[7] == 0);
    // group's 512 gather indices -> LDS (once)
    ldsIdx[tid] = is64 ? arr[2 * (g * CG + tid)] : arr[g * CG + tid];
    __syncthreads();

    // A-gather ownership: thread t = (row rl, k-octet oct) of the A tile
    const int rl  = tid >> 2;          // 0..127
    const int oct = tid & 3;           // 0..3
    const float* xrow = X + (size_t)(mt * BM + rl) * C_IN;
    // swizzled LDS dest (same layout the LDA reads expect)
    unsigned short* aw0 = &ldsA[0][(rl * 4 + (oct ^ ((rl >> 2) & 3))) * 8];
    unsigned short* aw1 = &ldsA[1][(rl * 4 + (oct ^ ((rl >> 2) & 3))) * 8];

    const unsigned short* Bb = Wb + (size_t)g * J_RANK * CG + (size_t)(nt * BN) * CG;

    f32x4 acc[4][4];
#pragma unroll
    for (int m = 0; m < 4; ++m)
#pragma unroll
        for (int n = 0; n < 4; ++n) acc[m][n] = (f32x4){0.f, 0.f, 0.f, 0.f};

    const int coff = (lkq ^ ((lr >> 2) & 3)) * 8;

#define STAGE_B(kt_)                                                          \
    do { const int p_ = (kt_) & 1;                                            \
        _Pragma("unroll")                                                     \
        for (int i_ = 0; i_ < 2; ++i_) {                                      \
            int c_ = i_ * 512 + tid;                                          \
            int rl_ = c_ >> 2, gc_ = (c_ & 3) ^ ((rl_ >> 2) & 3);             \
            __builtin_amdgcn_global_load_lds(                                 \
                (const __attribute__((address_space(1))) unsigned int*)       \
                    (Bb + (size_t)rl_ * CG + (kt_) * BK + gc_ * 8),           \
                (__attribute__((address_space(3))) unsigned int*)             \
                    (&ldsB[p_][0] + c_ * 8),                                  \
                16, 0, 0);                                                    \
        }                                                                     \
    } while (0)

// read (kt_)'s 8 indices from LDS and issue 8 scattered x loads
#define A_ISSUE(kt_)                                                          \
    do {                                                                      \
        ia = *(const int4*)&ldsIdx[(kt_) * 32 + oct * 8];                     \
        ib = *(const int4*)&ldsIdx[(kt_) * 32 + oct * 8 + 4];                 \
        s0 = xrow[ia.x]; s1 = xrow[ia.y]; s2 = xrow[ia.z]; s3 = xrow[ia.w];   \
        s4 = xrow[ib.x]; s5 = xrow[ib.y]; s6 = xrow[ib.z]; s7 = xrow[ib.w];   \
    } while (0)

#define A_WRITE(dst_)                                                         \
    do {                                                                      \
        u16x8 o_;                                                             \
        o_[0] = f2bf(s0); o_[1] = f2bf(s1); o_[2] = f2bf(s2); o_[3] = f2bf(s3);\
        o_[4] = f2bf(s4); o_[5] = f2bf(s5); o_[6] = f2bf(s6); o_[7] = f2bf(s7);\
        *(u16x8*)(dst_) = o_;                                                 \
    } while (0)

#define LDA(m_) (*(const bf16x8*)&ldsA[buf][(wr * 64 + (m_) * 16 + lr) * BK + coff])
#define LDB(n_) (*(const bf16x8*)&ldsB[buf][(wc * 64 + (n_) * 16 + lr) * BK + coff])

#define PHASE_TAIL()                                                          \
    __builtin_amdgcn_s_barrier();                                             \
    asm volatile("s_waitcnt lgkmcnt(0)" ::: "memory");                        \
    __builtin_amdgcn_sched_barrier(0);                                        \
    __builtin_amdgcn_s_setprio(1)

#define PHASE_END()                                                           \
    __builtin_amdgcn_s_setprio(0);                                            \
    __builtin_amdgcn_s_barrier()

    int4 ia, ib;
    float s0, s1, s2, s3, s4, s5, s6, s7;

    // ---- prologue: A(0) gather + B(0),B(1) DMA ----
    A_ISSUE(0);                                        // 8 VMEM (oldest)
    STAGE_B(0); STAGE_B(1);                            // 4 VMEM
    asm volatile("s_waitcnt vmcnt(4)" ::: "memory");   // scat8(0) retired
    A_WRITE(aw0);                                      // A(0) -> slot 0
    asm volatile("s_waitcnt vmcnt(2)" ::: "memory");   // B(0) landed
    asm volatile("s_waitcnt lgkmcnt(0)" ::: "memory"); // A-write retired
    __builtin_amdgcn_s_barrier();

    bf16x8 bfr[4], af[2];

    for (int kt = 0; kt < NKT; ++kt) {
        const int buf = kt & 1;

        // ---- phase 0: frag reads + issue A-gather(kt+1) ----
#pragma unroll
        for (int n = 0; n < 4; ++n) bfr[n] = LDB(n);
        af[0] = LDA(0); af[1] = LDA(1);
        if (kt + 1 < NKT) A_ISSUE(kt + 1);
        PHASE_TAIL();
#pragma unroll
        for (int mm = 0; mm < 2; ++mm)
#pragma unroll
            for (int n = 0; n < 4; ++n)
                acc[mm][n] = __builtin_amdgcn_mfma_f32_16x16x32_bf16(
                    af[mm], bfr[n], acc[mm][n], 0, 0, 0);
        PHASE_END();

        // ---- phase 1: frag reads + B(kt+2) DMA + A(kt+1) cvt/write ----
        af[0] = LDA(2); af[1] = LDA(3);
        if (kt + 2 < NKT) STAGE_B(kt + 2);
        if (kt + 1 < NKT) {
            if (kt == NKT - 2)
                asm volatile("s_waitcnt vmcnt(0)" ::: "memory");
            else  // retires [B(kt+1), scat8]; leaves B(kt+2) in flight
                asm volatile("s_waitcnt vmcnt(2)" ::: "memory");
            A_WRITE(buf ? aw0 : aw1);   // slot (kt+1)&1
        }
        PHASE_TAIL();
#pragma unroll
        for (int mm = 0; mm < 2; ++mm)
#pragma unroll
            for (int n = 0; n < 4; ++n)
                acc[2 + mm][n] = __builtin_amdgcn_mfma_f32_16x16x32_bf16(
                    af[mm], bfr[n], acc[2 + mm][n], 0, 0, 0);
        PHASE_END();
    }
#undef STAGE_B
#undef A_ISSUE
#undef A_WRITE
#undef LDA
#undef LDB
#undef PHASE_TAIL
#undef PHASE_END

    // epilogue: D frag layout col = lane&15, row = (lane>>4)*4 + r
    const int r0 = mt * BM + wr * 64 + (lkq << 2);
    const int cbase = nt * BN + wc * 64 + lr;   // within group's 512 cols
#pragma unroll
    for (int n = 0; n < 4; ++n) {
        int col = cbase + n * 16;
        float bv = bias[g * J_RANK + col];
#pragma unroll
        for (int m = 0; m < 4; ++m) {
            int row = r0 + m * 16;
            float* op = out + (size_t)row * C_IN + g * J_RANK + col;
#pragma unroll
            for (int r = 0; r < 4; ++r)
                op[(size_t)r * C_IN] = acc[m][n][r] + bv;
        }
    }
}

extern "C" void kernel_launch(void* const* d_in, const int* in_sizes, int n_in,
                              void* d_out, int out_size, void* d_ws, size_t ws_size,
                              hipStream_t stream) {
    const float* x    = (const float*)d_in[0];
    const int*   arr  = (const int*)d_in[1];
    const float* w    = (const float*)d_in[2];
    const float* bias = (const float*)d_in[3];
    float* out = (float*)d_out;

    // workspace: wb bf16 [8][512][512] (4MB) only -- xp eliminated
    unsigned short* wb = (unsigned short*)d_ws;

    hipLaunchKernelGGL(convert_w_kernel, dim3((G_GRP * J_RANK * CG / 4 + 255) / 256),
                       dim3(256), 0, stream, w, wb, G_GRP * J_RANK * CG / 4);
    hipLaunchKernelGGL(fused_gemm_kernel,
                       dim3(G_GRP * (B_ROWS / BM) * (J_RANK / BN)), dim3(512),
                       0, stream, x, arr, wb, bias, out);
}

// Round 12
// 102.227 us; speedup vs baseline: 7.6297x; 7.6297x over previous
//
#include <hip/hip_runtime.h>
#include <hip/hip_bf16.h>

#define B_ROWS 8192
#define C_IN   4096
#define G_GRP  8
#define CG     512
#define J_RANK 512

// ---- GEMM geometry: 128x256 tile, BK=32, 8 waves (2x4), wave tile 64x64 ----
#define BM 128
#define BN 256
#define BK 32
#define NKT (CG / BK)                 // 16 K-tiles

// ---- permute geometry ----
#define RPB    8                      // rows per permute block
#define PERM_BLOCKS (B_ROWS / RPB)    // 1024
#define CONV_BLOCKS 128               // w-conversion folded into same launch

typedef __attribute__((ext_vector_type(8))) short bf16x8;
typedef __attribute__((ext_vector_type(4))) float f32x4;
typedef __attribute__((ext_vector_type(8))) unsigned short u16x8;

struct ushort4v { unsigned short x, y, z, w; };

__device__ __forceinline__ unsigned short f2bf(float f) {
    unsigned int u = __float_as_uint(f);
    unsigned int r = (u + 0x7FFFu + ((u >> 16) & 1u)) >> 16;  // RNE
    return (unsigned short)r;
}

// ------ kernel 1: gather-permute x (single barrier/row) + w-convert -----
// Blocks [0, PERM_BLOCKS): permute. Blocks [PERM_BLOCKS, +CONV_BLOCKS):
// convert w fp32->bf16 (no barriers in that path).
// Permute: depth-3 LDS row pipeline, ONE barrier per row. Key invariant:
// at row r's start barrier every wave has consumed its row r-1 ds_reads
// (stores depend on them), so slot (r-1)%3 == (r+2)%3 is globally free --
// stage row r+2 there right after the barrier. vmcnt ladder (in-order,
// 4 loads + 2 stores per row, stage precedes stores in each step):
//   r0: 4   r1: 6   steady: 8   last: 4
__global__ __launch_bounds__(256) void permute_x_kernel(
    const float* __restrict__ x, const int* __restrict__ arr,
    unsigned short* __restrict__ xp,
    const float* __restrict__ w, unsigned short* __restrict__ wb) {
    const int tid = threadIdx.x;

    if (blockIdx.x >= PERM_BLOCKS) {
        // ---- w conversion path ----
        const int cb = blockIdx.x - PERM_BLOCKS;
#pragma unroll
        for (int t = 0; t < 16; ++t) {
            int i = cb * 4096 + t * 256 + tid;   // 128*4096 = 524288 float4s
            float4 v = ((const float4*)w)[i];
            ushort4v o;
            o.x = f2bf(v.x); o.y = f2bf(v.y); o.z = f2bf(v.z); o.w = f2bf(v.w);
            ((ushort4v*)wb)[i] = o;
        }
        return;
    }

    __shared__ float buf[3][C_IN];   // 48 KB -> 3 blocks/CU
    const int row0 = blockIdx.x * RPB;

    // arrangements declared int64 in the reference; harness may hand int32.
    // int64 little-endian => odd int32 words all 0 (values < 4096).
    const bool is64 = (arr[1] == 0 && arr[3] == 0 && arr[5] == 0 && arr[7] == 0);

    int sidx[16];
#pragma unroll
    for (int pass = 0; pass < 2; ++pass)
#pragma unroll
        for (int k = 0; k < 8; ++k) {
            int p = pass * 2048 + tid * 8 + k;
            sidx[pass * 8 + k] = is64 ? arr[2 * p] : arr[p];
        }

#define PSTAGE(bufi, r)                                                      \
    do {                                                                     \
        const float* src_ = x + (size_t)(row0 + (r)) * C_IN;                 \
        _Pragma("unroll")                                                    \
        for (int i_ = 0; i_ < 4; ++i_) {                                     \
            int c_ = i_ * 256 + tid;                                         \
            __builtin_amdgcn_global_load_lds(                                \
                (const __attribute__((address_space(1))) unsigned int*)      \
                    (src_ + c_ * 4),                                         \
                (__attribute__((address_space(3))) unsigned int*)            \
                    (&buf[bufi][0] + c_ * 4),                                \
                16, 0, 0);                                                   \
        }                                                                    \
    } while (0)

    PSTAGE(0, 0);
    PSTAGE(1, 1);

#pragma unroll
    for (int r = 0; r < RPB; ++r) {
        if (r == 0)            asm volatile("s_waitcnt vmcnt(4)" ::: "memory");
        else if (r == 1)       asm volatile("s_waitcnt vmcnt(6)" ::: "memory");
        else if (r == RPB - 1) asm volatile("s_waitcnt vmcnt(4)" ::: "memory");
        else                   asm volatile("s_waitcnt vmcnt(8)" ::: "memory");
        __builtin_amdgcn_s_barrier();          // all waves' row r in LDS;
                                               // AND all row r-1 reads consumed
        __builtin_amdgcn_sched_barrier(0);

        // slot (r+2)%3 == (r-1)%3: its row r-1 reads are done -> overwrite OK
        if (r + 2 < RPB) PSTAGE((r + 2) % 3, r + 2);

        const int bi = r % 3;
        unsigned short* orow = xp + (size_t)(row0 + r) * C_IN;
#pragma unroll
        for (int pass = 0; pass < 2; ++pass) {
            u16x8 o;
#pragma unroll
            for (int k = 0; k < 8; ++k)
                o[k] = f2bf(buf[bi][sidx[pass * 8 + k]]);
            *(u16x8*)(orow + pass * 2048 + tid * 8) = o;
        }
        __builtin_amdgcn_sched_barrier(0);
    }
#undef PSTAGE
}

// -------- kernel 2: grouped GEMM, 128x256/BK32, 2-phase, 2 blocks/CU ----
// (byte-identical to R9 -- best measured)
__global__ __launch_bounds__(512, 4) void gemm_kernel(
    const unsigned short* __restrict__ Xp,   // [B][4096] bf16 (permuted)
    const unsigned short* __restrict__ Wb,   // [G][J][CG] bf16
    const float* __restrict__ bias,          // [G][J]
    float* __restrict__ out) {               // [B][4096] fp32
    __shared__ unsigned short ldsA[3][BM * BK];   // 3 x 8 KB
    __shared__ unsigned short ldsB[2][BN * BK];   // 2 x 16 KB

    const int tid = threadIdx.x;
    const int g   = blockIdx.x & 7;
    const int idx = blockIdx.x >> 3;   // 0..127
    const int mt  = idx >> 1;          // 0..63
    const int nt  = idx & 1;

    const int l   = tid & 63;
    const int wv  = tid >> 6;          // 0..7
    const int wr  = wv >> 2;           // 0..1  (M half: rows wr*64..+63)
    const int wc  = wv & 3;            // 0..3  (N quarter: cols wc*64..+63)
    const int lr  = l & 15;
    const int lkq = l >> 4;            // 0..3

    const unsigned short* Ab = Xp + (size_t)(mt * BM) * C_IN + g * CG;
    const unsigned short* Bb = Wb + (size_t)g * J_RANK * CG + (size_t)(nt * BN) * CG;

    f32x4 acc[4][4];
#pragma unroll
    for (int m = 0; m < 4; ++m)
#pragma unroll
        for (int n = 0; n < 4; ++n) acc[m][n] = (f32x4){0.f, 0.f, 0.f, 0.f};

    // read offset within a row: chunk lkq, swizzled by row bits 2-3 (=lr>>2)
    const int coff = (lkq ^ ((lr >> 2) & 3)) * 8;

#define STAGE_A(kt_)                                                          \
    do { const int p_ = (kt_) % 3;                                            \
        int c_ = tid;                                                         \
        int rl_ = c_ >> 2, gc_ = (c_ & 3) ^ ((rl_ >> 2) & 3);                 \
        __builtin_amdgcn_global_load_lds(                                     \
            (const __attribute__((address_space(1))) unsigned int*)           \
                (Ab + (size_t)rl_ * C_IN + (kt_) * BK + gc_ * 8),             \
            (__attribute__((address_space(3))) unsigned int*)                 \
                (&ldsA[p_][0] + c_ * 8),                                      \
            16, 0, 0);                                                        \
    } while (0)

#define STAGE_B(kt_)                                                          \
    do { const int p_ = (kt_) & 1;                                            \
        _Pragma("unroll")                                                     \
        for (int i_ = 0; i_ < 2; ++i_) {                                      \
            int c_ = i_ * 512 + tid;                                          \
            int rl_ = c_ >> 2, gc_ = (c_ & 3) ^ ((rl_ >> 2) & 3);             \
            __builtin_amdgcn_global_load_lds(                                 \
                (const __attribute__((address_space(1))) unsigned int*)       \
                    (Bb + (size_t)rl_ * CG + (kt_) * BK + gc_ * 8),           \
                (__attribute__((address_space(3))) unsigned int*)             \
                    (&ldsB[p_][0] + c_ * 8),                                  \
                16, 0, 0);                                                    \
        }                                                                     \
    } while (0)

#define LDA(m_) (*(const bf16x8*)&ldsA[bufA][(wr * 64 + (m_) * 16 + lr) * BK + coff])
#define LDB(n_) (*(const bf16x8*)&ldsB[bufB][(wc * 64 + (n_) * 16 + lr) * BK + coff])

#define PHASE_TAIL()                                                          \
    __builtin_amdgcn_s_barrier();                                             \
    asm volatile("s_waitcnt lgkmcnt(0)" ::: "memory");                        \
    __builtin_amdgcn_sched_barrier(0);                                        \
    __builtin_amdgcn_s_setprio(1)

#define PHASE_END()                                                           \
    __builtin_amdgcn_s_setprio(0);                                            \
    __builtin_amdgcn_s_barrier()

    // ---- prologue: stage kt0, kt1 (3 instrs each); wait kt0 landed ----
    STAGE_A(0); STAGE_B(0);
    STAGE_A(1); STAGE_B(1);
    asm volatile("s_waitcnt vmcnt(3)" ::: "memory");
    __builtin_amdgcn_s_barrier();

    bf16x8 bfr[4], af[2];

    for (int kt = 0; kt < NKT; ++kt) {
        const int bufA = kt % 3;
        const int bufB = kt & 1;

        // ---- phase 0: read B(all 4) + A(m0,m1); stage A(kt+2) ----
#pragma unroll
        for (int n = 0; n < 4; ++n) bfr[n] = LDB(n);
        af[0] = LDA(0); af[1] = LDA(1);
        if (kt + 2 < NKT) STAGE_A(kt + 2);
        PHASE_TAIL();
#pragma unroll
        for (int mm = 0; mm < 2; ++mm)
#pragma unroll
            for (int n = 0; n < 4; ++n)
                acc[mm][n] = __builtin_amdgcn_mfma_f32_16x16x32_bf16(
                    af[mm], bfr[n], acc[mm][n], 0, 0, 0);
        PHASE_END();

        // ---- phase 1: read A(m2,m3); stage B(kt+2); counted vmcnt ----
        af[0] = LDA(2); af[1] = LDA(3);
        if (kt + 2 < NKT) STAGE_B(kt + 2);
        if (kt <= NKT - 3)      asm volatile("s_waitcnt vmcnt(3)" ::: "memory");
        else if (kt == NKT - 2) asm volatile("s_waitcnt vmcnt(0)" ::: "memory");
        PHASE_TAIL();
#pragma unroll
        for (int mm = 0; mm < 2; ++mm)
#pragma unroll
            for (int n = 0; n < 4; ++n)
                acc[2 + mm][n] = __builtin_amdgcn_mfma_f32_16x16x32_bf16(
                    af[mm], bfr[n], acc[2 + mm][n], 0, 0, 0);
        PHASE_END();
    }
#undef STAGE_A
#undef STAGE_B
#undef LDA
#undef LDB
#undef PHASE_TAIL
#undef PHASE_END

    // epilogue: D frag layout col = lane&15, row = (lane>>4)*4 + r
    const int r0 = mt * BM + wr * 64 + (lkq << 2);
    const int cbase = nt * BN + wc * 64 + lr;   // within group's 512 cols
#pragma unroll
    for (int n = 0; n < 4; ++n) {
        int col = cbase + n * 16;
        float bv = bias[g * J_RANK + col];
#pragma unroll
        for (int m = 0; m < 4; ++m) {
            int row = r0 + m * 16;
            float* op = out + (size_t)row * C_IN + g * J_RANK + col;
#pragma unroll
            for (int r = 0; r < 4; ++r)
                op[(size_t)r * C_IN] = acc[m][n][r] + bv;
        }
    }
}

extern "C" void kernel_launch(void* const* d_in, const int* in_sizes, int n_in,
                              void* d_out, int out_size, void* d_ws, size_t ws_size,
                              hipStream_t stream) {
    const float* x    = (const float*)d_in[0];
    const int*   arr  = (const int*)d_in[1];
    const float* w    = (const float*)d_in[2];
    const float* bias = (const float*)d_in[3];
    float* out = (float*)d_out;

    // workspace: xp bf16 [8192][4096] (64MB) | wb bf16 [8][512][512] (4MB)
    unsigned short* xp = (unsigned short*)d_ws;
    unsigned short* wb = xp + (size_t)B_ROWS * C_IN;

    hipLaunchKernelGGL(permute_x_kernel, dim3(PERM_BLOCKS + CONV_BLOCKS),
                       dim3(256), 0, stream, x, arr, xp, w, wb);
    hipLaunchKernelGGL(gemm_kernel,
                       dim3(G_GRP * (B_ROWS / BM) * (J_RANK / BN)), dim3(512),
                       0, stream, xp, wb, bias, out);
}